// Round 2
// 237.807 us; speedup vs baseline: 1.1509x; 1.1509x over previous
//
#include <hip/hip_runtime.h>
#include <math.h>

// IDMRFLoss on MI355X — R13 == R12 resubmit (round-1 bench died at the
// container level with no compile/verify signal; kernel re-audited: no
// divergent barriers, no OOB global_load_lds, wave-uniform LDS dests).
// gemm_all: global_load_lds staging (m97 recipe), double-buffered LDS, BK=32.
// R11 was latency-bound (MfmaUtil 14.6%: 256B/wave in flight vs ~600cyc L3
// latency). All other kernels identical to R11 (273.7us measured).
//
// Layer 0 (relu3_2): B=4, C=256, S=4096, weight 1.0
// Layer 1 (relu4_2): B=4, C=512, S=1024, weight 2.0 (style + content)
//
// Swizzled operand layout (per batch, matrix [S][K] bf16):
//   elem(row,k) at ((row>>4)*(K/8) + (k>>3))*128 + (row&15)*8 + (k&7)
//   => a (row16-group, 4 k-chunks) BK=32 slice is 512 elems (1KB) CONTIGUOUS,
//      so global_load_lds stages it linearly; ds_read_b128 frags conflict-free.
// sim blocked bf16 layout (per 128x128 block at (by,bx)):
//   elem = (by*nQB+bx)*16384 + slot*4096 + (t*4+u)*256 + quad*64 + lm*4 + r
//   p = by*128+(slot&1)*64+t*16+quad*4+r ; q = bx*128+(slot>>1)*64+u*16+lm
//
// Math (per combo): c1 = 1/((1-colmax)/2+eps); log2 domain c1L=c1*log2e,
// c0L=(2-c1)*log2e; colsum_q = sum_p 2^(c0L+c1L*v);
// kmax_p = 2^(max_q (c0L - log2(colsum_q) + c1L*v)); loss = sum -w*log(mean kmax).

#define MRF_EPS 1e-5f
#define LOG2E 1.44269504088896340736f

typedef __attribute__((ext_vector_type(8))) short bf16x8;
typedef __attribute__((ext_vector_type(4))) float f32x4;
typedef unsigned short ushort_t;
struct __align__(8) ushort4_t { ushort_t x, y, z, w; };
struct __align__(16) ushort8_t { ushort_t v[8]; };

__device__ __forceinline__ ushort_t f2bf(float x) {
    unsigned u = __float_as_uint(x);
    u += 0x7FFFu + ((u >> 16) & 1u);
    return (ushort_t)(u >> 16);
}
__device__ __forceinline__ float bf2f(ushort_t u) {
    return __uint_as_float(((unsigned)u) << 16);
}

// async global->LDS, 16B per lane. LDS dest is wave-uniform base + lane*16;
// global src is per-lane. Generic->AS(3) is lowered by LLVM as a truncation
// to the low 32 bits (apertures are 4GiB-aligned), so the uintptr cast is the
// standard way to materialize the AS(3) pointer from a flat __shared__ addr.
typedef __attribute__((address_space(1))) const unsigned int gu32;
typedef __attribute__((address_space(3))) unsigned int lu32;
__device__ __forceinline__ void gload16(const ushort_t* g, ushort_t* l) {
    __builtin_amdgcn_global_load_lds((gu32*)(uintptr_t)g, (lu32*)(uintptr_t)l,
                                     16, 0, 0);
}

// ================= stats =================
__global__ __launch_bounds__(256) void stats_all(
    const float* __restrict__ gen3, const float* __restrict__ tar3,
    const float* __restrict__ gen4, const float* __restrict__ tar4,
    float* __restrict__ mean3, float* __restrict__ rg3, float* __restrict__ rt3,
    float* __restrict__ mean4, float* __restrict__ rg4, float* __restrict__ rt4) {
    const float *gen, *tar; float *mean, *rg, *rt; int C, S, b, bx;
    int bid = blockIdx.x;
    if (bid < 256) {            // layer4 first (heavier per block)
        C = 512; S = 1024; b = bid >> 6; bx = bid & 63;
        gen = gen4; tar = tar4; mean = mean4; rg = rg4; rt = rt4;
    } else {
        bid -= 256;
        C = 256; S = 4096; b = bid >> 8; bx = bid & 255;
        gen = gen3; tar = tar3; mean = mean3; rg = rg3; rt = rt3;
    }
    int tid = threadIdx.x, pq = tid & 3, cs = tid >> 2;
    int s0 = bx * 16 + pq * 4;
    const float* g = gen + (size_t)b * C * S + s0;
    const float* t = tar + (size_t)b * C * S + s0;

    f32x4 st = {0.f, 0.f, 0.f, 0.f}, st2 = st, sg = st, sg2 = st;
    for (int c = cs; c < C; c += 64) {
        f32x4 tv = *(const f32x4*)(t + (size_t)c * S);
        f32x4 gv = *(const f32x4*)(g + (size_t)c * S);
        st += tv; st2 += tv * tv; sg += gv; sg2 += gv * gv;
    }
    __shared__ f32x4 red[4][4][64];
    __shared__ f32x4 red2[4][4][4];
    red[0][pq][cs] = st; red[1][pq][cs] = st2; red[2][pq][cs] = sg; red[3][pq][cs] = sg2;
    __syncthreads();
    if (tid < 64) {
        int s_ = tid >> 4, p_ = (tid >> 2) & 3, part = tid & 3;
        f32x4 s = red[s_][p_][part * 16];
#pragma unroll
        for (int j = 1; j < 16; j++) s += red[s_][p_][part * 16 + j];
        red2[s_][p_][part] = s;
    }
    __syncthreads();
    if (tid < 4) {
        f32x4 sts = red2[0][tid][0] + red2[0][tid][1] + red2[0][tid][2] + red2[0][tid][3];
        f32x4 st2s = red2[1][tid][0] + red2[1][tid][1] + red2[1][tid][2] + red2[1][tid][3];
        f32x4 sgs = red2[2][tid][0] + red2[2][tid][1] + red2[2][tid][2] + red2[2][tid][3];
        f32x4 sg2s = red2[3][tid][0] + red2[3][tid][1] + red2[3][tid][2] + red2[3][tid][3];
        f32x4 m, vrt, vrg;
        float invC = 1.f / (float)C;
#pragma unroll
        for (int e = 0; e < 4; e++) {
            float mm = sts[e] * invC;
            m[e] = mm;
            vrt[e] = rsqrtf(st2s[e] - mm * sts[e]);
            vrg[e] = rsqrtf(sg2s[e] - 2.f * mm * sgs[e] + mm * sts[e]);
        }
        int idx = b * S + bx * 16 + tid * 4;
        *(f32x4*)(mean + idx) = m;
        *(f32x4*)(rt + idx) = vrt;
        *(f32x4*)(rg + idx) = vrg;
    }
}

// ================= apply =================
__global__ __launch_bounds__(256) void apply_all(
    const float* __restrict__ gen3, const float* __restrict__ tar3,
    const float* __restrict__ gen4, const float* __restrict__ tar4,
    const float* __restrict__ mean3, const float* __restrict__ rg3, const float* __restrict__ rt3,
    const float* __restrict__ mean4, const float* __restrict__ rg4, const float* __restrict__ rt4,
    ushort_t* __restrict__ gnT3, ushort_t* __restrict__ tnT3,
    ushort_t* __restrict__ gnT4, ushort_t* __restrict__ tnT4) {
    const float *gen, *tar, *mean, *rg, *rt; ushort_t *gnT, *tnT;
    int C, S, b, sxb, cyb;
    int bid = blockIdx.x;
    if (bid < 512) {            // layer4: 4 z * (16 x 8)
        C = 512; S = 1024; b = bid >> 7; int rem = bid & 127;
        cyb = rem >> 4; sxb = rem & 15;
        gen = gen4; tar = tar4; mean = mean4; rg = rg4; rt = rt4; gnT = gnT4; tnT = tnT4;
    } else {                    // layer3: 4 z * (64 x 4)
        bid -= 512;
        C = 256; S = 4096; b = bid >> 8; int rem = bid & 255;
        cyb = rem >> 6; sxb = rem & 63;
        gen = gen3; tar = tar3; mean = mean3; rg = rg3; rt = rt3; gnT = gnT3; tnT = tnT3;
    }
    int tid = threadIdx.x;
    int s0 = sxb * 64, c0 = cyb * 64;
    const float* g = gen + (size_t)b * C * S;
    const float* t = tar + (size_t)b * C * S;
    int tx = tid & 63, tw = tid >> 6;
    int sidx = b * S + s0 + tx;
    float m = mean[sidx], rgv = rg[sidx], rtv = rt[sidx];

    __shared__ ushort_t tg[64][72], tt_[64][72];
#pragma unroll
    for (int i = 0; i < 16; i++) {
        int cl = tw * 16 + i;
        float gv = g[(size_t)(c0 + cl) * S + s0 + tx];
        float tv = t[(size_t)(c0 + cl) * S + s0 + tx];
        tg[tx][cl] = f2bf((gv - m) * rgv);
        tt_[tx][cl] = f2bf((tv - m) * rtv);
    }
    __syncthreads();
    int KC = C >> 3;
#pragma unroll
    for (int j = 0; j < 2; j++) {
        int p = j * 256 + tid;
        int s = p & 63, ch = p >> 6;
        int row = s0 + s;
        int r16 = row >> 4, lm = row & 15;
        size_t off = (size_t)b * S * C + (((size_t)r16 * KC + (c0 >> 3) + ch) * 16 + lm) * 8;
        *(ushort8_t*)(gnT + off) = *(const ushort8_t*)&tg[s][ch * 8];
        *(ushort8_t*)(tnT + off) = *(const ushort8_t*)&tt_[s][ch * 8];
    }
}

// ================= gemm (LDS-staged, double-buffered, BK=32) =================
// Per 128x128 output tile: per BK=32 step stage A-slice (8KB) + B-slice (8KB)
// into LDS via 16 x 1KB global_load_lds issues (4 per wave), double-buffered.
// Each wave then ds_read_b128's its 4 A + 4 B frags and does 16 MFMA.
// MFMA accumulation order identical to R11 (bit-exact results).
template <int K>
__device__ __forceinline__ void gemm_body(
    const ushort_t* __restrict__ A, const ushort_t* __restrict__ B,
    ushort_t* __restrict__ sim, float* __restrict__ cmPart,
    int S, int bx, int by, ushort_t* __restrict__ lds) {
    const int tid = threadIdx.x;
    const int lane = tid & 63, wave = tid >> 6;
    const int wm = (wave & 1) * 64, wn = (wave >> 1) * 64;
    const int lm = lane & 15, quad = lane >> 4;
    const int p0 = by * 128, q0 = bx * 128;

    constexpr int KC = K / 8;    // k-chunks per row-group
    constexpr int KB = K / 32;   // BK=32 steps

    // 16 segments/step: s=0..7 -> A row16-group by*8+s ; s=8..15 -> B group
    // bx*8+(s-8). Each segment = 512 elems (1KB) contiguous in the swizzled
    // layout. This wave stages segments s = wave*4 + i, i=0..3.
    const ushort_t* segsrc[4];
    ushort_t* segdst[4];
#pragma unroll
    for (int i = 0; i < 4; i++) {
        int s = wave * 4 + i;
        segsrc[i] = (s < 8)
            ? A + ((size_t)(by * 8 + s) * KC) * 128 + lane * 8
            : B + ((size_t)(bx * 8 + (s - 8)) * KC) * 128 + lane * 8;
        segdst[i] = lds + s * 512;   // A at [0,4096), B at [4096,8192) elems
    }

    auto stage = [&](int buf, int kb) {
#pragma unroll
        for (int i = 0; i < 4; i++)
            gload16(segsrc[i] + (size_t)kb * 512, segdst[i] + buf * 8192);
    };

    f32x4 acc[4][4];
#pragma unroll
    for (int t = 0; t < 4; t++)
#pragma unroll
        for (int u = 0; u < 4; u++) acc[t][u] = (f32x4){0.f, 0.f, 0.f, 0.f};

    stage(0, 0);
    __syncthreads();   // drains vmcnt(0): buf0 ready

    // frag base addrs within a buffer (elems): A: ((wm>>4)+t)*512+quad*128+lm*8
    const ushort_t* lA = lds + (wm >> 4) * 512 + quad * 128 + lm * 8;
    const ushort_t* lB = lds + 4096 + (wn >> 4) * 512 + quad * 128 + lm * 8;

#pragma unroll 2
    for (int kb = 0; kb < KB; kb++) {
        int cur = (kb & 1) * 8192;
        if (kb + 1 < KB) stage((kb & 1) ^ 1, kb + 1);   // prefetch next slice
        bf16x8 a[4], b[4];
#pragma unroll
        for (int t = 0; t < 4; t++) {
            a[t] = *(const bf16x8*)(lA + cur + t * 512);
            b[t] = *(const bf16x8*)(lB + cur + t * 512);
        }
#pragma unroll
        for (int t = 0; t < 4; t++)
#pragma unroll
            for (int u = 0; u < 4; u++)
                acc[t][u] = __builtin_amdgcn_mfma_f32_16x16x32_bf16(a[t], b[u], acc[t][u], 0, 0, 0);
        __syncthreads();   // drains vmcnt(0)+lgkmcnt(0): next buf ready, cur buf free
    }

    int nQB = S >> 7;
    size_t base = ((size_t)(by * nQB + bx)) * 16384
                + (size_t)(wave * 4096 + quad * 64 + lm * 4);
    float cmax[4] = {-INFINITY, -INFINITY, -INFINITY, -INFINITY};
#pragma unroll
    for (int t = 0; t < 4; t++)
#pragma unroll
        for (int u = 0; u < 4; u++) {
            f32x4 v = acc[t][u];
            ushort4_t o;
            o.x = f2bf(v.x); o.y = f2bf(v.y); o.z = f2bf(v.z); o.w = f2bf(v.w);
            *(ushort4_t*)(sim + base + (t * 4 + u) * 256) = o;
            float mx = fmaxf(fmaxf(bf2f(o.x), bf2f(o.y)), fmaxf(bf2f(o.z), bf2f(o.w)));
            cmax[u] = fmaxf(cmax[u], mx);
        }
    int r = by * 2 + (wave & 1);
#pragma unroll
    for (int u = 0; u < 4; u++) {
        float m = cmax[u];
        m = fmaxf(m, __shfl_xor(m, 16, 64));
        m = fmaxf(m, __shfl_xor(m, 32, 64));
        if (lane < 16) cmPart[(size_t)r * S + q0 + wn + u * 16 + lane] = m;
    }
}

__global__ __launch_bounds__(256) void gemm_all(
    const ushort_t* __restrict__ tnT3, const ushort_t* __restrict__ gnT3,
    ushort_t* __restrict__ sim3, float* __restrict__ cmPart3,
    const ushort_t* __restrict__ tnT4, const ushort_t* __restrict__ gnT4,
    ushort_t* __restrict__ sim4, float* __restrict__ cmPart4) {
    __shared__ ushort_t lds[16384];   // 2 bufs x (A 8KB + B 8KB) = 32 KB
    int bid = blockIdx.x;
    if (bid < 256) {            // layer4 first (2x K per block)
        int z = bid >> 6, rem = bid & 63, by = rem >> 3, bx = rem & 7;
        gemm_body<512>(tnT4 + (size_t)z * 524288, gnT4 + (size_t)z * 524288,
                       sim4 + (size_t)z * 1048576, cmPart4 + (size_t)z * 16384,
                       1024, bx, by, lds);
    } else {
        bid -= 256;
        int z = bid >> 10, rem = bid & 1023, by = rem >> 5, bx = rem & 31;
        gemm_body<256>(tnT3 + (size_t)z * 1048576, gnT3 + (size_t)z * 1048576,
                       sim3 + (size_t)z * 16777216, cmPart3 + (size_t)z * 262144,
                       4096, bx, by, lds);
    }
}

// ================= colmax reduce -> coef, zero colsum + acc =================
__global__ __launch_bounds__(256) void colmax_reduce_all(
    const float* __restrict__ cmPart3, float2* __restrict__ coef3, float* __restrict__ colsum3,
    const float* __restrict__ cmPart4, float2* __restrict__ coef4, float* __restrict__ colsum4,
    float* __restrict__ acc) {
    const float* cmPart; float2* coef; float* colsum; int S, R, qb, accIdx;
    int bid = blockIdx.x;
    if (bid < 16) {             // layer4: 4 z * 4 blocks
        int z = bid >> 2; qb = bid & 3; S = 1024; R = 16; accIdx = 4 + z;
        cmPart = cmPart4 + (size_t)z * 16384; coef = coef4 + (size_t)z * 1024;
        colsum = colsum4 + (size_t)z * 1024;
    } else {
        bid -= 16;
        int z = bid >> 4; qb = bid & 15; S = 4096; R = 64; accIdx = z;
        cmPart = cmPart3 + (size_t)z * 262144; coef = coef3 + (size_t)z * 4096;
        colsum = colsum3 + (size_t)z * 4096;
    }
    if (qb == 0 && threadIdx.x == 0) acc[accIdx] = 0.f;
    int q = qb * 256 + threadIdx.x;
    float m = cmPart[q];
    for (int r = 1; r < R; r++) m = fmaxf(m, cmPart[(size_t)r * S + q]);
    float c1 = 1.f / ((1.f - m) * 0.5f + MRF_EPS);
    coef[q] = make_float2((2.f - c1) * LOG2E, c1 * LOG2E);
    colsum[q] = 0.f;
}

// ================= colsum =================
__global__ __launch_bounds__(256) void colsum_all(
    const ushort_t* __restrict__ sim3, const float2* __restrict__ coef3, float* __restrict__ colsum3,
    const ushort_t* __restrict__ sim4, const float2* __restrict__ coef4, float* __restrict__ colsum4) {
    const ushort_t* sim; const float2* coef; float* colsum; int S, bx, by;
    int bid = blockIdx.x;
    if (bid < 256) {            // layer4: 4 z * (8 x 8)
        int z = bid >> 6, rem = bid & 63; by = rem >> 3; bx = rem & 7; S = 1024;
        sim = sim4 + (size_t)z * 1048576; coef = coef4 + (size_t)z * 1024;
        colsum = colsum4 + (size_t)z * 1024;
    } else {
        bid -= 256;
        int z = bid >> 10, rem = bid & 1023; by = rem >> 5; bx = rem & 31; S = 4096;
        sim = sim3 + (size_t)z * 16777216; coef = coef3 + (size_t)z * 4096;
        colsum = colsum3 + (size_t)z * 4096;
    }
    int tid = threadIdx.x, lane = tid & 63;
    int u = lane >> 4, lm = lane & 15;
    int sub = (tid >> 6) & 1, cg = tid >> 7;
    int nQB = S >> 7;
    int q = bx * 128 + cg * 64 + u * 16 + lm;
    float2 cc = coef[q];
    float c0 = cc.x, c1 = cc.y;
    const ushort_t* base = sim + ((size_t)(by * nQB + bx)) * 16384
                         + (size_t)((sub | (cg << 1)) * 4096 + u * 256 + lm * 4);
    float s = 0.f;
#pragma unroll
    for (int t = 0; t < 4; t++)
#pragma unroll
        for (int quad = 0; quad < 4; quad++) {
            ushort4_t w = *(const ushort4_t*)(base + t * 1024 + quad * 64);
            s += exp2f(c0 + c1 * bf2f(w.x)) + exp2f(c0 + c1 * bf2f(w.y))
               + exp2f(c0 + c1 * bf2f(w.z)) + exp2f(c0 + c1 * bf2f(w.w));
        }
    atomicAdd(colsum + q, s);
}

// ================= rowmax (inline fold: c0' = c0 - log2(colsum)) =================
__global__ __launch_bounds__(256) void rowmax_all(
    const ushort_t* __restrict__ sim3, const float2* __restrict__ coef3, const float* __restrict__ colsum3,
    const ushort_t* __restrict__ sim4, const float2* __restrict__ coef4, const float* __restrict__ colsum4,
    float* __restrict__ acc) {
    const ushort_t* sim; const float2* coef; const float* colsum;
    int S, blk; float* accSlot;
    int bid = blockIdx.x;
    if (bid < 1024) {           // layer3 first (4x q-scan per block)
        int z = bid >> 8; blk = bid & 255; S = 4096; accSlot = acc + z;
        sim = sim3 + (size_t)z * 16777216; coef = coef3 + (size_t)z * 4096;
        colsum = colsum3 + (size_t)z * 4096;
    } else {
        bid -= 1024;
        int z = bid >> 6; blk = bid & 63; S = 1024; accSlot = acc + 4 + z;
        sim = sim4 + (size_t)z * 1048576; coef = coef4 + (size_t)z * 1024;
        colsum = colsum4 + (size_t)z * 1024;
    }
    int wave = threadIdx.x >> 6, lane = threadIdx.x & 63;
    int g = blk * 4 + wave;
    int by = g >> 5, rem = g & 31;
    int sub = rem >> 4, t = (rem >> 2) & 3, quad = rem & 3;
    int u = lane >> 4, lm = lane & 15;
    int nQB = S >> 7;
    f32x4 m = {-INFINITY, -INFINITY, -INFINITY, -INFINITY};
    for (int bx = 0; bx < nQB; bx++) {
#pragma unroll
        for (int cg = 0; cg < 2; cg++) {
            int q = bx * 128 + cg * 64 + u * 16 + lm;
            float2 cc = coef[q];
            float c0p = cc.x - log2f(colsum[q]);
            const ushort_t* ptr = sim + ((size_t)(by * nQB + bx)) * 16384
                                + (size_t)((sub | (cg << 1)) * 4096 + (t * 4 + u) * 256 + quad * 64 + lm * 4);
            ushort4_t w = *(const ushort4_t*)ptr;
            m[0] = fmaxf(m[0], c0p + cc.y * bf2f(w.x));
            m[1] = fmaxf(m[1], c0p + cc.y * bf2f(w.y));
            m[2] = fmaxf(m[2], c0p + cc.y * bf2f(w.z));
            m[3] = fmaxf(m[3], c0p + cc.y * bf2f(w.w));
        }
    }
#pragma unroll
    for (int off = 32; off >= 1; off >>= 1)
#pragma unroll
        for (int e = 0; e < 4; e++)
            m[e] = fmaxf(m[e], __shfl_xor(m[e], off, 64));
    __shared__ float partial[4];
    if (lane == 0)
        partial[wave] = exp2f(m[0]) + exp2f(m[1]) + exp2f(m[2]) + exp2f(m[3]);
    __syncthreads();
    if (threadIdx.x == 0)
        atomicAdd(accSlot, partial[0] + partial[1] + partial[2] + partial[3]);
}

__global__ void finalize_kernel(const float* __restrict__ acc, float* __restrict__ out) {
    float loss = 0.f;
    for (int b = 0; b < 4; b++) loss += -logf(acc[b] * (1.f / 4096.f));
    for (int b = 0; b < 4; b++) loss += -2.f * logf(acc[4 + b] * (1.f / 1024.f));
    out[0] = loss;
}

extern "C" void kernel_launch(void* const* d_in, const int* in_sizes, int n_in,
                              void* d_out, int out_size, void* d_ws, size_t ws_size,
                              hipStream_t stream) {
    const float* gen3 = (const float*)d_in[0];
    const float* tar3 = (const float*)d_in[1];
    const float* gen4 = (const float*)d_in[2];
    const float* tar4 = (const float*)d_in[3];

    char* wsb = (char*)d_ws;
    size_t off = 0;
    auto alloc = [&](size_t bytes) {
        void* p = wsb + off;
        off += (bytes + 255) & ~(size_t)255;
        return p;
    };
    // layer3 (z=4): S=4096, C=256, R=64
    ushort_t* sim3 = (ushort_t*)alloc((size_t)4 * 16777216 * 2);   // 134.2 MB
    ushort_t* gnT3 = (ushort_t*)alloc((size_t)4 * 1048576 * 2);    // 8.4 MB
    ushort_t* tnT3 = (ushort_t*)alloc((size_t)4 * 1048576 * 2);    // 8.4 MB
    float* cmPart3 = (float*)alloc((size_t)4 * 262144 * 4);        // 4.2 MB
    float2* coef3 = (float2*)alloc((size_t)4 * 4096 * 8);
    float* colsum3 = (float*)alloc((size_t)4 * 4096 * 4);
    float* mean3 = (float*)alloc((size_t)4 * 4096 * 4);
    float* rg3 = (float*)alloc((size_t)4 * 4096 * 4);
    float* rt3 = (float*)alloc((size_t)4 * 4096 * 4);
    // layer4 (z=4): S=1024, C=512, R=16
    ushort_t* sim4 = (ushort_t*)alloc((size_t)4 * 1048576 * 2);    // 8.4 MB
    ushort_t* gnT4 = (ushort_t*)alloc((size_t)4 * 524288 * 2);     // 4.2 MB
    ushort_t* tnT4 = (ushort_t*)alloc((size_t)4 * 524288 * 2);     // 4.2 MB
    float* cmPart4 = (float*)alloc((size_t)4 * 16384 * 4);
    float2* coef4 = (float2*)alloc((size_t)4 * 1024 * 8);
    float* colsum4 = (float*)alloc((size_t)4 * 1024 * 4);
    float* mean4 = (float*)alloc((size_t)4 * 1024 * 4);
    float* rg4 = (float*)alloc((size_t)4 * 1024 * 4);
    float* rt4 = (float*)alloc((size_t)4 * 1024 * 4);
    float* acc = (float*)alloc(64 * 4);
    // total ~173 MB (ws is 256 MiB per the harness poison fill)

    stats_all<<<256 + 1024, 256, 0, stream>>>(
        gen3, tar3, gen4, tar4, mean3, rg3, rt3, mean4, rg4, rt4);
    apply_all<<<512 + 1024, 256, 0, stream>>>(
        gen3, tar3, gen4, tar4, mean3, rg3, rt3, mean4, rg4, rt4,
        gnT3, tnT3, gnT4, tnT4);
    gemm_all<<<256 + 4096, 256, 0, stream>>>(
        tnT3, gnT3, sim3, cmPart3, tnT4, gnT4, sim4, cmPart4);
    colmax_reduce_all<<<16 + 64, 256, 0, stream>>>(
        cmPart3, coef3, colsum3, cmPart4, coef4, colsum4, acc);
    colsum_all<<<256 + 4096, 256, 0, stream>>>(
        sim3, coef3, colsum3, sim4, coef4, colsum4);
    rowmax_all<<<1024 + 256, 256, 0, stream>>>(
        sim3, coef3, colsum3, sim4, coef4, colsum4, acc);
    finalize_kernel<<<1, 1, 0, stream>>>(acc, (float*)d_out);
}

// Round 3
// 228.107 us; speedup vs baseline: 1.1998x; 1.0425x over previous
//
#include <hip/hip_runtime.h>
#include <math.h>

// IDMRFLoss on MI355X — R14: gemm_all K-loop upgraded R13 -> T4 counted-vmcnt
// 2-deep pipeline, 3 LDS buffers (48KB). R13's __syncthreads drained the
// just-issued prefetch (vmcnt(0)) every K-step -> ~1kcy stall/step. Now:
// stage(kb+2) each iter; end-of-iter wait is s_waitcnt vmcnt(4) + raw
// s_barrier, leaving the newest 4 loads/wave in flight across the barrier.
// MFMA accumulation order identical to R13 (bit-exact, absmax 0.0).
// All non-gemm kernels identical to R13 (237.8us measured, gemm 67.8us).
//
// Layer 0 (relu3_2): B=4, C=256, S=4096, weight 1.0
// Layer 1 (relu4_2): B=4, C=512, S=1024, weight 2.0 (style + content)
//
// Swizzled operand layout (per batch, matrix [S][K] bf16):
//   elem(row,k) at ((row>>4)*(K/8) + (k>>3))*128 + (row&15)*8 + (k&7)
//   => a (row16-group, 4 k-chunks) BK=32 slice is 512 elems (1KB) CONTIGUOUS,
//      so global_load_lds stages it linearly; ds_read_b128 frags conflict-free.
// sim blocked bf16 layout (per 128x128 block at (by,bx)):
//   elem = (by*nQB+bx)*16384 + slot*4096 + (t*4+u)*256 + quad*64 + lm*4 + r
//   p = by*128+(slot&1)*64+t*16+quad*4+r ; q = bx*128+(slot>>1)*64+u*16+lm
//
// Math (per combo): c1 = 1/((1-colmax)/2+eps); log2 domain c1L=c1*log2e,
// c0L=(2-c1)*log2e; colsum_q = sum_p 2^(c0L+c1L*v);
// kmax_p = 2^(max_q (c0L - log2(colsum_q) + c1L*v)); loss = sum -w*log(mean kmax).

#define MRF_EPS 1e-5f
#define LOG2E 1.44269504088896340736f

typedef __attribute__((ext_vector_type(8))) short bf16x8;
typedef __attribute__((ext_vector_type(4))) float f32x4;
typedef unsigned short ushort_t;
struct __align__(8) ushort4_t { ushort_t x, y, z, w; };
struct __align__(16) ushort8_t { ushort_t v[8]; };

__device__ __forceinline__ ushort_t f2bf(float x) {
    unsigned u = __float_as_uint(x);
    u += 0x7FFFu + ((u >> 16) & 1u);
    return (ushort_t)(u >> 16);
}
__device__ __forceinline__ float bf2f(ushort_t u) {
    return __uint_as_float(((unsigned)u) << 16);
}

// async global->LDS, 16B per lane. LDS dest is wave-uniform base + lane*16;
// global src is per-lane. Generic->AS(3) lowers to a low-32-bit truncation
// (apertures are 4GiB-aligned), so the uintptr cast is safe.
typedef __attribute__((address_space(1))) const unsigned int gu32;
typedef __attribute__((address_space(3))) unsigned int lu32;
__device__ __forceinline__ void gload16(const ushort_t* g, ushort_t* l) {
    __builtin_amdgcn_global_load_lds((gu32*)(uintptr_t)g, (lu32*)(uintptr_t)l,
                                     16, 0, 0);
}

// ================= stats =================
__global__ __launch_bounds__(256) void stats_all(
    const float* __restrict__ gen3, const float* __restrict__ tar3,
    const float* __restrict__ gen4, const float* __restrict__ tar4,
    float* __restrict__ mean3, float* __restrict__ rg3, float* __restrict__ rt3,
    float* __restrict__ mean4, float* __restrict__ rg4, float* __restrict__ rt4) {
    const float *gen, *tar; float *mean, *rg, *rt; int C, S, b, bx;
    int bid = blockIdx.x;
    if (bid < 256) {            // layer4 first (heavier per block)
        C = 512; S = 1024; b = bid >> 6; bx = bid & 63;
        gen = gen4; tar = tar4; mean = mean4; rg = rg4; rt = rt4;
    } else {
        bid -= 256;
        C = 256; S = 4096; b = bid >> 8; bx = bid & 255;
        gen = gen3; tar = tar3; mean = mean3; rg = rg3; rt = rt3;
    }
    int tid = threadIdx.x, pq = tid & 3, cs = tid >> 2;
    int s0 = bx * 16 + pq * 4;
    const float* g = gen + (size_t)b * C * S + s0;
    const float* t = tar + (size_t)b * C * S + s0;

    f32x4 st = {0.f, 0.f, 0.f, 0.f}, st2 = st, sg = st, sg2 = st;
    for (int c = cs; c < C; c += 64) {
        f32x4 tv = *(const f32x4*)(t + (size_t)c * S);
        f32x4 gv = *(const f32x4*)(g + (size_t)c * S);
        st += tv; st2 += tv * tv; sg += gv; sg2 += gv * gv;
    }
    __shared__ f32x4 red[4][4][64];
    __shared__ f32x4 red2[4][4][4];
    red[0][pq][cs] = st; red[1][pq][cs] = st2; red[2][pq][cs] = sg; red[3][pq][cs] = sg2;
    __syncthreads();
    if (tid < 64) {
        int s_ = tid >> 4, p_ = (tid >> 2) & 3, part = tid & 3;
        f32x4 s = red[s_][p_][part * 16];
#pragma unroll
        for (int j = 1; j < 16; j++) s += red[s_][p_][part * 16 + j];
        red2[s_][p_][part] = s;
    }
    __syncthreads();
    if (tid < 4) {
        f32x4 sts = red2[0][tid][0] + red2[0][tid][1] + red2[0][tid][2] + red2[0][tid][3];
        f32x4 st2s = red2[1][tid][0] + red2[1][tid][1] + red2[1][tid][2] + red2[1][tid][3];
        f32x4 sgs = red2[2][tid][0] + red2[2][tid][1] + red2[2][tid][2] + red2[2][tid][3];
        f32x4 sg2s = red2[3][tid][0] + red2[3][tid][1] + red2[3][tid][2] + red2[3][tid][3];
        f32x4 m, vrt, vrg;
        float invC = 1.f / (float)C;
#pragma unroll
        for (int e = 0; e < 4; e++) {
            float mm = sts[e] * invC;
            m[e] = mm;
            vrt[e] = rsqrtf(st2s[e] - mm * sts[e]);
            vrg[e] = rsqrtf(sg2s[e] - 2.f * mm * sgs[e] + mm * sts[e]);
        }
        int idx = b * S + bx * 16 + tid * 4;
        *(f32x4*)(mean + idx) = m;
        *(f32x4*)(rt + idx) = vrt;
        *(f32x4*)(rg + idx) = vrg;
    }
}

// ================= apply =================
__global__ __launch_bounds__(256) void apply_all(
    const float* __restrict__ gen3, const float* __restrict__ tar3,
    const float* __restrict__ gen4, const float* __restrict__ tar4,
    const float* __restrict__ mean3, const float* __restrict__ rg3, const float* __restrict__ rt3,
    const float* __restrict__ mean4, const float* __restrict__ rg4, const float* __restrict__ rt4,
    ushort_t* __restrict__ gnT3, ushort_t* __restrict__ tnT3,
    ushort_t* __restrict__ gnT4, ushort_t* __restrict__ tnT4) {
    const float *gen, *tar, *mean, *rg, *rt; ushort_t *gnT, *tnT;
    int C, S, b, sxb, cyb;
    int bid = blockIdx.x;
    if (bid < 512) {            // layer4: 4 z * (16 x 8)
        C = 512; S = 1024; b = bid >> 7; int rem = bid & 127;
        cyb = rem >> 4; sxb = rem & 15;
        gen = gen4; tar = tar4; mean = mean4; rg = rg4; rt = rt4; gnT = gnT4; tnT = tnT4;
    } else {                    // layer3: 4 z * (64 x 4)
        bid -= 512;
        C = 256; S = 4096; b = bid >> 8; int rem = bid & 255;
        cyb = rem >> 6; sxb = rem & 63;
        gen = gen3; tar = tar3; mean = mean3; rg = rg3; rt = rt3; gnT = gnT3; tnT = tnT3;
    }
    int tid = threadIdx.x;
    int s0 = sxb * 64, c0 = cyb * 64;
    const float* g = gen + (size_t)b * C * S;
    const float* t = tar + (size_t)b * C * S;
    int tx = tid & 63, tw = tid >> 6;
    int sidx = b * S + s0 + tx;
    float m = mean[sidx], rgv = rg[sidx], rtv = rt[sidx];

    __shared__ ushort_t tg[64][72], tt_[64][72];
#pragma unroll
    for (int i = 0; i < 16; i++) {
        int cl = tw * 16 + i;
        float gv = g[(size_t)(c0 + cl) * S + s0 + tx];
        float tv = t[(size_t)(c0 + cl) * S + s0 + tx];
        tg[tx][cl] = f2bf((gv - m) * rgv);
        tt_[tx][cl] = f2bf((tv - m) * rtv);
    }
    __syncthreads();
    int KC = C >> 3;
#pragma unroll
    for (int j = 0; j < 2; j++) {
        int p = j * 256 + tid;
        int s = p & 63, ch = p >> 6;
        int row = s0 + s;
        int r16 = row >> 4, lm = row & 15;
        size_t off = (size_t)b * S * C + (((size_t)r16 * KC + (c0 >> 3) + ch) * 16 + lm) * 8;
        *(ushort8_t*)(gnT + off) = *(const ushort8_t*)&tg[s][ch * 8];
        *(ushort8_t*)(tnT + off) = *(const ushort8_t*)&tt_[s][ch * 8];
    }
}

// ===== gemm (R14: 3-buffer LDS, 2-deep prefetch, counted vmcnt) =====
// Per 128x128 tile, per BK=32 step: 16KB slice staged via 16 x 1KB
// global_load_lds (4/wave). Loop: stage(kb+2) -> ds_read buf[kb%3] ->
// lgkmcnt(0)+sched_barrier -> 16 MFMA -> vmcnt(4) [kb+1 landed, kb+2 in
// flight] -> s_barrier. Each load gets ~2 iterations to land.
template <int K>
__device__ __forceinline__ void gemm_body(
    const ushort_t* __restrict__ A, const ushort_t* __restrict__ B,
    ushort_t* __restrict__ sim, float* __restrict__ cmPart,
    int S, int bx, int by, ushort_t* __restrict__ lds) {
    const int tid = threadIdx.x;
    const int lane = tid & 63, wave = tid >> 6;
    const int wm = (wave & 1) * 64, wn = (wave >> 1) * 64;
    const int lm = lane & 15, quad = lane >> 4;
    const int q0 = bx * 128;

    constexpr int KC = K / 8;    // k-chunks per row-group
    constexpr int KB = K / 32;   // BK=32 steps

    // 16 segments/step: s=0..7 -> A row16-group by*8+s ; s=8..15 -> B group
    // bx*8+(s-8). Each segment = 512 elems (1KB) contiguous. This wave
    // stages segments s = wave*4 + i, i=0..3.
    const ushort_t* segsrc[4];
    ushort_t* segdst[4];
#pragma unroll
    for (int i = 0; i < 4; i++) {
        int s = wave * 4 + i;
        segsrc[i] = (s < 8)
            ? A + ((size_t)(by * 8 + s) * KC) * 128 + lane * 8
            : B + ((size_t)(bx * 8 + (s - 8)) * KC) * 128 + lane * 8;
        segdst[i] = lds + s * 512;   // A at [0,4096), B at [4096,8192) elems
    }

    auto stage = [&](int buf, int kb) {
#pragma unroll
        for (int i = 0; i < 4; i++)
            gload16(segsrc[i] + (size_t)kb * 512, segdst[i] + buf * 8192);
    };

    f32x4 acc[4][4];
#pragma unroll
    for (int t = 0; t < 4; t++)
#pragma unroll
        for (int u = 0; u < 4; u++) acc[t][u] = (f32x4){0.f, 0.f, 0.f, 0.f};

    // prologue: 2 slices in flight; wait for slice 0 only (vmcnt 8 -> 4).
    stage(0, 0);
    stage(1, 1);
    asm volatile("s_waitcnt vmcnt(4)" ::: "memory");
    __builtin_amdgcn_s_barrier();

    // frag base addrs within a buffer (elems): A: ((wm>>4)+t)*512+quad*128+lm*8
    const ushort_t* lA = lds + (wm >> 4) * 512 + quad * 128 + lm * 8;
    const ushort_t* lB = lds + 4096 + (wn >> 4) * 512 + quad * 128 + lm * 8;

#pragma unroll
    for (int kb = 0; kb < KB; kb++) {
        const int cur = (kb % 3) * 8192;   // compile-time (full unroll)
        // stage kb+2 into the buffer freed at end of iter kb-1
        if (kb + 2 < KB) stage((kb + 2) % 3, kb + 2);
        bf16x8 a[4], b[4];
#pragma unroll
        for (int t = 0; t < 4; t++) {
            a[t] = *(const bf16x8*)(lA + cur + t * 512);
            b[t] = *(const bf16x8*)(lB + cur + t * 512);
        }
        asm volatile("s_waitcnt lgkmcnt(0)" ::: "memory");
        __builtin_amdgcn_sched_barrier(0);   // rule 18: pin MFMA below lgkmcnt
#pragma unroll
        for (int t = 0; t < 4; t++)
#pragma unroll
            for (int u = 0; u < 4; u++)
                acc[t][u] = __builtin_amdgcn_mfma_f32_16x16x32_bf16(a[t], b[u], acc[t][u], 0, 0, 0);
        if (kb + 1 < KB) {
            // wait for kb+1's 4 loads; leave kb+2's 4 in flight (if staged)
            if (kb + 2 < KB) asm volatile("s_waitcnt vmcnt(4)" ::: "memory");
            else             asm volatile("s_waitcnt vmcnt(0)" ::: "memory");
            __builtin_amdgcn_s_barrier();
        }
    }

    int nQB = S >> 7;
    size_t base = ((size_t)(by * nQB + bx)) * 16384
                + (size_t)(wave * 4096 + quad * 64 + lm * 4);
    float cmax[4] = {-INFINITY, -INFINITY, -INFINITY, -INFINITY};
#pragma unroll
    for (int t = 0; t < 4; t++)
#pragma unroll
        for (int u = 0; u < 4; u++) {
            f32x4 v = acc[t][u];
            ushort4_t o;
            o.x = f2bf(v.x); o.y = f2bf(v.y); o.z = f2bf(v.z); o.w = f2bf(v.w);
            *(ushort4_t*)(sim + base + (t * 4 + u) * 256) = o;
            float mx = fmaxf(fmaxf(bf2f(o.x), bf2f(o.y)), fmaxf(bf2f(o.z), bf2f(o.w)));
            cmax[u] = fmaxf(cmax[u], mx);
        }
    int r = by * 2 + (wave & 1);
#pragma unroll
    for (int u = 0; u < 4; u++) {
        float m = cmax[u];
        m = fmaxf(m, __shfl_xor(m, 16, 64));
        m = fmaxf(m, __shfl_xor(m, 32, 64));
        if (lane < 16) cmPart[(size_t)r * S + q0 + wn + u * 16 + lane] = m;
    }
}

__global__ __launch_bounds__(256) void gemm_all(
    const ushort_t* __restrict__ tnT3, const ushort_t* __restrict__ gnT3,
    ushort_t* __restrict__ sim3, float* __restrict__ cmPart3,
    const ushort_t* __restrict__ tnT4, const ushort_t* __restrict__ gnT4,
    ushort_t* __restrict__ sim4, float* __restrict__ cmPart4) {
    __shared__ ushort_t lds[24576];   // 3 bufs x (A 8KB + B 8KB) = 48 KB
    int bid = blockIdx.x;
    if (bid < 256) {            // layer4 first (2x K per block)
        int z = bid >> 6, rem = bid & 63, by = rem >> 3, bx = rem & 7;
        gemm_body<512>(tnT4 + (size_t)z * 524288, gnT4 + (size_t)z * 524288,
                       sim4 + (size_t)z * 1048576, cmPart4 + (size_t)z * 16384,
                       1024, bx, by, lds);
    } else {
        bid -= 256;
        int z = bid >> 10, rem = bid & 1023, by = rem >> 5, bx = rem & 31;
        gemm_body<256>(tnT3 + (size_t)z * 1048576, gnT3 + (size_t)z * 1048576,
                       sim3 + (size_t)z * 16777216, cmPart3 + (size_t)z * 262144,
                       4096, bx, by, lds);
    }
}

// ================= colmax reduce -> coef, zero colsum + acc =================
__global__ __launch_bounds__(256) void colmax_reduce_all(
    const float* __restrict__ cmPart3, float2* __restrict__ coef3, float* __restrict__ colsum3,
    const float* __restrict__ cmPart4, float2* __restrict__ coef4, float* __restrict__ colsum4,
    float* __restrict__ acc) {
    const float* cmPart; float2* coef; float* colsum; int S, R, qb, accIdx;
    int bid = blockIdx.x;
    if (bid < 16) {             // layer4: 4 z * 4 blocks
        int z = bid >> 2; qb = bid & 3; S = 1024; R = 16; accIdx = 4 + z;
        cmPart = cmPart4 + (size_t)z * 16384; coef = coef4 + (size_t)z * 1024;
        colsum = colsum4 + (size_t)z * 1024;
    } else {
        bid -= 16;
        int z = bid >> 4; qb = bid & 15; S = 4096; R = 64; accIdx = z;
        cmPart = cmPart3 + (size_t)z * 262144; coef = coef3 + (size_t)z * 4096;
        colsum = colsum3 + (size_t)z * 4096;
    }
    if (qb == 0 && threadIdx.x == 0) acc[accIdx] = 0.f;
    int q = qb * 256 + threadIdx.x;
    float m = cmPart[q];
    for (int r = 1; r < R; r++) m = fmaxf(m, cmPart[(size_t)r * S + q]);
    float c1 = 1.f / ((1.f - m) * 0.5f + MRF_EPS);
    coef[q] = make_float2((2.f - c1) * LOG2E, c1 * LOG2E);
    colsum[q] = 0.f;
}

// ================= colsum =================
__global__ __launch_bounds__(256) void colsum_all(
    const ushort_t* __restrict__ sim3, const float2* __restrict__ coef3, float* __restrict__ colsum3,
    const ushort_t* __restrict__ sim4, const float2* __restrict__ coef4, float* __restrict__ colsum4) {
    const ushort_t* sim; const float2* coef; float* colsum; int S, bx, by;
    int bid = blockIdx.x;
    if (bid < 256) {            // layer4: 4 z * (8 x 8)
        int z = bid >> 6, rem = bid & 63; by = rem >> 3; bx = rem & 7; S = 1024;
        sim = sim4 + (size_t)z * 1048576; coef = coef4 + (size_t)z * 1024;
        colsum = colsum4 + (size_t)z * 1024;
    } else {
        bid -= 256;
        int z = bid >> 10, rem = bid & 1023; by = rem >> 5; bx = rem & 31; S = 4096;
        sim = sim3 + (size_t)z * 16777216; coef = coef3 + (size_t)z * 4096;
        colsum = colsum3 + (size_t)z * 4096;
    }
    int tid = threadIdx.x, lane = tid & 63;
    int u = lane >> 4, lm = lane & 15;
    int sub = (tid >> 6) & 1, cg = tid >> 7;
    int nQB = S >> 7;
    int q = bx * 128 + cg * 64 + u * 16 + lm;
    float2 cc = coef[q];
    float c0 = cc.x, c1 = cc.y;
    const ushort_t* base = sim + ((size_t)(by * nQB + bx)) * 16384
                         + (size_t)((sub | (cg << 1)) * 4096 + u * 256 + lm * 4);
    float s = 0.f;
#pragma unroll
    for (int t = 0; t < 4; t++)
#pragma unroll
        for (int quad = 0; quad < 4; quad++) {
            ushort4_t w = *(const ushort4_t*)(base + t * 1024 + quad * 64);
            s += exp2f(c0 + c1 * bf2f(w.x)) + exp2f(c0 + c1 * bf2f(w.y))
               + exp2f(c0 + c1 * bf2f(w.z)) + exp2f(c0 + c1 * bf2f(w.w));
        }
    atomicAdd(colsum + q, s);
}

// ================= rowmax (inline fold: c0' = c0 - log2(colsum)) =================
__global__ __launch_bounds__(256) void rowmax_all(
    const ushort_t* __restrict__ sim3, const float2* __restrict__ coef3, const float* __restrict__ colsum3,
    const ushort_t* __restrict__ sim4, const float2* __restrict__ coef4, const float* __restrict__ colsum4,
    float* __restrict__ acc) {
    const ushort_t* sim; const float2* coef; const float* colsum;
    int S, blk; float* accSlot;
    int bid = blockIdx.x;
    if (bid < 1024) {           // layer3 first (4x q-scan per block)
        int z = bid >> 8; blk = bid & 255; S = 4096; accSlot = acc + z;
        sim = sim3 + (size_t)z * 16777216; coef = coef3 + (size_t)z * 4096;
        colsum = colsum3 + (size_t)z * 4096;
    } else {
        bid -= 1024;
        int z = bid >> 6; blk = bid & 63; S = 1024; accSlot = acc + 4 + z;
        sim = sim4 + (size_t)z * 1048576; coef = coef4 + (size_t)z * 1024;
        colsum = colsum4 + (size_t)z * 1024;
    }
    int wave = threadIdx.x >> 6, lane = threadIdx.x & 63;
    int g = blk * 4 + wave;
    int by = g >> 5, rem = g & 31;
    int sub = rem >> 4, t = (rem >> 2) & 3, quad = rem & 3;
    int u = lane >> 4, lm = lane & 15;
    int nQB = S >> 7;
    f32x4 m = {-INFINITY, -INFINITY, -INFINITY, -INFINITY};
    for (int bx = 0; bx < nQB; bx++) {
#pragma unroll
        for (int cg = 0; cg < 2; cg++) {
            int q = bx * 128 + cg * 64 + u * 16 + lm;
            float2 cc = coef[q];
            float c0p = cc.x - log2f(colsum[q]);
            const ushort_t* ptr = sim + ((size_t)(by * nQB + bx)) * 16384
                                + (size_t)((sub | (cg << 1)) * 4096 + (t * 4 + u) * 256 + quad * 64 + lm * 4);
            ushort4_t w = *(const ushort4_t*)ptr;
            m[0] = fmaxf(m[0], c0p + cc.y * bf2f(w.x));
            m[1] = fmaxf(m[1], c0p + cc.y * bf2f(w.y));
            m[2] = fmaxf(m[2], c0p + cc.y * bf2f(w.z));
            m[3] = fmaxf(m[3], c0p + cc.y * bf2f(w.w));
        }
    }
#pragma unroll
    for (int off = 32; off >= 1; off >>= 1)
#pragma unroll
        for (int e = 0; e < 4; e++)
            m[e] = fmaxf(m[e], __shfl_xor(m[e], off, 64));
    __shared__ float partial[4];
    if (lane == 0)
        partial[wave] = exp2f(m[0]) + exp2f(m[1]) + exp2f(m[2]) + exp2f(m[3]);
    __syncthreads();
    if (threadIdx.x == 0)
        atomicAdd(accSlot, partial[0] + partial[1] + partial[2] + partial[3]);
}

__global__ void finalize_kernel(const float* __restrict__ acc, float* __restrict__ out) {
    float loss = 0.f;
    for (int b = 0; b < 4; b++) loss += -logf(acc[b] * (1.f / 4096.f));
    for (int b = 0; b < 4; b++) loss += -2.f * logf(acc[4 + b] * (1.f / 1024.f));
    out[0] = loss;
}

extern "C" void kernel_launch(void* const* d_in, const int* in_sizes, int n_in,
                              void* d_out, int out_size, void* d_ws, size_t ws_size,
                              hipStream_t stream) {
    const float* gen3 = (const float*)d_in[0];
    const float* tar3 = (const float*)d_in[1];
    const float* gen4 = (const float*)d_in[2];
    const float* tar4 = (const float*)d_in[3];

    char* wsb = (char*)d_ws;
    size_t off = 0;
    auto alloc = [&](size_t bytes) {
        void* p = wsb + off;
        off += (bytes + 255) & ~(size_t)255;
        return p;
    };
    // layer3 (z=4): S=4096, C=256, R=64
    ushort_t* sim3 = (ushort_t*)alloc((size_t)4 * 16777216 * 2);   // 134.2 MB
    ushort_t* gnT3 = (ushort_t*)alloc((size_t)4 * 1048576 * 2);    // 8.4 MB
    ushort_t* tnT3 = (ushort_t*)alloc((size_t)4 * 1048576 * 2);    // 8.4 MB
    float* cmPart3 = (float*)alloc((size_t)4 * 262144 * 4);        // 4.2 MB
    float2* coef3 = (float2*)alloc((size_t)4 * 4096 * 8);
    float* colsum3 = (float*)alloc((size_t)4 * 4096 * 4);
    float* mean3 = (float*)alloc((size_t)4 * 4096 * 4);
    float* rg3 = (float*)alloc((size_t)4 * 4096 * 4);
    float* rt3 = (float*)alloc((size_t)4 * 4096 * 4);
    // layer4 (z=4): S=1024, C=512, R=16
    ushort_t* sim4 = (ushort_t*)alloc((size_t)4 * 1048576 * 2);    // 8.4 MB
    ushort_t* gnT4 = (ushort_t*)alloc((size_t)4 * 524288 * 2);     // 4.2 MB
    ushort_t* tnT4 = (ushort_t*)alloc((size_t)4 * 524288 * 2);     // 4.2 MB
    float* cmPart4 = (float*)alloc((size_t)4 * 16384 * 4);
    float2* coef4 = (float2*)alloc((size_t)4 * 1024 * 8);
    float* colsum4 = (float*)alloc((size_t)4 * 1024 * 4);
    float* mean4 = (float*)alloc((size_t)4 * 1024 * 4);
    float* rg4 = (float*)alloc((size_t)4 * 1024 * 4);
    float* rt4 = (float*)alloc((size_t)4 * 1024 * 4);
    float* acc = (float*)alloc(64 * 4);
    // total ~173 MB (ws is 256 MiB per the harness poison fill)

    stats_all<<<256 + 1024, 256, 0, stream>>>(
        gen3, tar3, gen4, tar4, mean3, rg3, rt3, mean4, rg4, rt4);
    apply_all<<<512 + 1024, 256, 0, stream>>>(
        gen3, tar3, gen4, tar4, mean3, rg3, rt3, mean4, rg4, rt4,
        gnT3, tnT3, gnT4, tnT4);
    gemm_all<<<256 + 4096, 256, 0, stream>>>(
        tnT3, gnT3, sim3, cmPart3, tnT4, gnT4, sim4, cmPart4);
    colmax_reduce_all<<<16 + 64, 256, 0, stream>>>(
        cmPart3, coef3, colsum3, cmPart4, coef4, colsum4, acc);
    colsum_all<<<256 + 4096, 256, 0, stream>>>(
        sim3, coef3, colsum3, sim4, coef4, colsum4);
    rowmax_all<<<1024 + 256, 256, 0, stream>>>(
        sim3, coef3, colsum3, sim4, coef4, colsum4, acc);
    finalize_kernel<<<1, 1, 0, stream>>>(acc, (float*)d_out);
}